// Round 7
// baseline (185.451 us; speedup 1.0000x reference)
//
#include <hip/hip_runtime.h>
#include <math.h>

#define SDIM 256
#define CH 5
#define ROWF (SDIM * CH)      // 1280 floats per image row
#define NCHUNK 32             // K1 row-chunks per image
#define CHROWS 8              // rows per K1 block
#define GRAYF 0.9999f         // 0.2989+0.5870+0.1140
// d_ws layout (floats): part[NCHUNK][64][CH] | wbuf[64][512] (wy[256],wx[256] per image)
#define WBUF_OFF (NCHUNK * 64 * CH)

// ============ K0: per-image resample weight vectors (once, not per chunk) ============
__global__ __launch_bounds__(256) void aug_weights_kernel(
    const float* __restrict__ off_frac,
    const int*   __restrict__ crop_size,
    const int*   __restrict__ do_crop,
    float* __restrict__ wbuf)     // [64][512]
{
    const int b   = blockIdx.x;
    const int tid = threadIdx.x;

    __shared__ float wyl[SDIM];
    __shared__ float wxl[SDIM];

    const bool  docrop = do_crop[b] != 0;
    const float size_f = docrop ? (float)crop_size[b] : 256.0f;
    const float scale  = size_f * (1.0f / 256.0f);
    const float span   = 256.0f - size_f + 1.0f;
    const float off0   = docrop ? floorf(off_frac[2 * b + 0] * span) : 0.0f;
    const float off1   = docrop ? floorf(off_frac[2 * b + 1] * span) : 0.0f;

    wyl[tid] = 0.0f;
    wxl[tid] = 0.0f;
    __syncthreads();

    {   // scatter per-axis resample weights (tid = output coordinate)
        const float cy = ((float)tid + 0.5f) * scale - 0.5f + off0;
        const float fl = floorf(cy);
        const float fy = cy - fl;
        const int r0 = min(max((int)fl, 0), 255);
        const int r1 = min(max((int)fl + 1, 0), 255);
        atomicAdd(&wyl[r0], 1.0f - fy);
        atomicAdd(&wyl[r1], fy);

        const float cx = ((float)tid + 0.5f) * scale - 0.5f + off1;
        const float fl2 = floorf(cx);
        const float fx  = cx - fl2;
        const int c0 = min(max((int)fl2, 0), 255);
        const int c1 = min(max((int)fl2 + 1, 0), 255);
        atomicAdd(&wxl[c0], 1.0f - fx);
        atomicAdd(&wxl[c1], fx);
    }
    __syncthreads();

    wbuf[(size_t)b * 512 + tid]       = wyl[tid];
    wbuf[(size_t)b * 512 + 256 + tid] = wxl[tid];
}

// ============ K1: per-(b,ch) sum of resampled image — pure streaming reduce ============
// sum(bilinear_resample(A)) = sum_{r,j} A[r,j]*wy[r]*wx[j]; flip/rot90 leave the
// mean invariant. No LDS staging, no atomics; weights come from K0 via L2.
__global__ __launch_bounds__(256) void aug_sums_kernel(
    const float* __restrict__ crops,
    const float* __restrict__ wbuf,
    float* __restrict__ part)     // [NCHUNK][64][CH], fully written
{
    const int chunk = blockIdx.x;
    const int b     = blockIdx.y;
    const int tid   = threadIdx.x;

    __shared__ float psum[4][CH];

    const float* srcbase = crops + ((size_t)b * SDIM + (size_t)chunk * CHROWS) * ROWF;
    const int rA = tid >> 6;        // item 0 row (wave-uniform)
    const int rB = rA + 4;          // item 1 row
    const int t  = tid & 63;        // 4-pixel chunk in row

    const float4* pA = reinterpret_cast<const float4*>(srcbase + rA * ROWF + t * 20);
    const float4* pB = reinterpret_cast<const float4*>(srcbase + rB * ROWF + t * 20);
    // issue all loads before any use (MLP)
    const float4 a0 = pA[0], a1 = pA[1], a2 = pA[2], a3 = pA[3], a4 = pA[4];
    const float4 b0 = pB[0], b1 = pB[1], b2 = pB[2], b3 = pB[3], b4 = pB[4];
    const float4 wx = reinterpret_cast<const float4*>(wbuf + (size_t)b * 512 + 256)[t];
    const float wrA = wbuf[(size_t)b * 512 + chunk * CHROWS + rA];
    const float wrB = wbuf[(size_t)b * 512 + chunk * CHROWS + rB];

    float acc[5] = {0.0f, 0.0f, 0.0f, 0.0f, 0.0f};
    {
        const float w0 = wx.x * wrA, w1 = wx.y * wrA, w2 = wx.z * wrA, w3 = wx.w * wrA;
        acc[0] += a0.x * w0; acc[1] += a0.y * w0; acc[2] += a0.z * w0; acc[3] += a0.w * w0;
        acc[4] += a1.x * w0; acc[0] += a1.y * w1; acc[1] += a1.z * w1; acc[2] += a1.w * w1;
        acc[3] += a2.x * w1; acc[4] += a2.y * w1; acc[0] += a2.z * w2; acc[1] += a2.w * w2;
        acc[2] += a3.x * w2; acc[3] += a3.y * w2; acc[4] += a3.z * w2; acc[0] += a3.w * w3;
        acc[1] += a4.x * w3; acc[2] += a4.y * w3; acc[3] += a4.z * w3; acc[4] += a4.w * w3;
    }
    {
        const float w0 = wx.x * wrB, w1 = wx.y * wrB, w2 = wx.z * wrB, w3 = wx.w * wrB;
        acc[0] += b0.x * w0; acc[1] += b0.y * w0; acc[2] += b0.z * w0; acc[3] += b0.w * w0;
        acc[4] += b1.x * w0; acc[0] += b1.y * w1; acc[1] += b1.z * w1; acc[2] += b1.w * w1;
        acc[3] += b2.x * w1; acc[4] += b2.y * w1; acc[0] += b2.z * w2; acc[1] += b2.w * w2;
        acc[2] += b3.x * w2; acc[3] += b3.y * w2; acc[4] += b3.z * w2; acc[0] += b3.w * w3;
        acc[1] += b4.x * w3; acc[2] += b4.y * w3; acc[3] += b4.z * w3; acc[4] += b4.w * w3;
    }

    const int lane = tid & 63;
    const int wv   = tid >> 6;
    #pragma unroll
    for (int ch = 0; ch < CH; ++ch) {
        float s = acc[ch];
        #pragma unroll
        for (int o = 32; o > 0; o >>= 1) s += __shfl_down(s, o, 64);
        if (lane == 0) psum[wv][ch] = s;
    }
    __syncthreads();
    if (tid == 0) {
        #pragma unroll
        for (int ch = 0; ch < CH; ++ch)
            part[((size_t)chunk * 64 + b) * CH + ch] =
                psum[0][ch] + psum[1][ch] + psum[2][ch] + psum[3][ch];
    }
}

// ============ K2: 4 output rows/block; stride-64 pixel map; no-crop fast paths ============
__global__ __launch_bounds__(256) void aug_out_kernel(
    const float* __restrict__ crops,
    const float* __restrict__ off_frac,
    const int*   __restrict__ crop_size,
    const int*   __restrict__ do_crop,
    const int*   __restrict__ flip,
    const int*   __restrict__ rot_k,
    const float* __restrict__ part,
    const float* __restrict__ bright,
    const float* __restrict__ contrast,
    float* __restrict__ out)
{
    const int oi0  = blockIdx.x * 4;   // first output row of this block
    const int b    = blockIdx.y;
    const int tid  = threadIdx.x;
    const int rr   = tid >> 6;         // output row within block (wave-uniform)
    const int lane = tid & 63;         // lane owns pixels lane+64p, p=0..3

    // union: even-k stage 5*1280 | odd-k stage 28*260 | obuf 4*1280
    __shared__ __align__(16) float smem[28 * 260];
    __shared__ float prm[2 * CH];

    const bool  docrop = do_crop[b] != 0;
    const float size_f = docrop ? (float)crop_size[b] : 256.0f;
    const float scale  = size_f * (1.0f / 256.0f);
    const float span   = 256.0f - size_f + 1.0f;
    const float off0   = docrop ? floorf(off_frac[2 * b + 0] * span) : 0.0f;
    const float off1   = docrop ? floorf(off_frac[2 * b + 1] * span) : 0.0f;
    const int   k      = rot_k[b] & 3;
    const bool  flp    = flip[b] != 0;

    if (tid < CH) {   // per-channel affine out = v*aa + ab (before first sync)
        float s = 0.0f;
        #pragma unroll
        for (int p = 0; p < NCHUNK; ++p) s += part[((size_t)p * 64 + b) * CH + tid];
        const float m  = s * (1.0f / 65536.0f);
        const float co = contrast[b * CH + tid];
        const float br = bright[b * CH + tid];
        prm[tid]      = co * GRAYF;
        prm[CH + tid] = ((1.0f - co) * m + br) * GRAYF;
    }

    float vout[20];   // vout[p*5+ch] for pixel oj = lane + 64p

    if ((k & 1) == 0) {
        // ---- even k: src row <- oi (wave-uniform), src col <- oj ----
        const int y_min = (k == 0) ? oi0 : 255 - (oi0 + 3);
        const float cymin = ((float)y_min + 0.5f) * scale - 0.5f + off0;
        const int rbase = (int)floorf(cymin);
        const int nst   = docrop ? 5 : 4;    // staged input rows

        const float4* src4 = reinterpret_cast<const float4*>(crops + (size_t)b * SDIM * ROWF);
        float4* dst4 = reinterpret_cast<float4*>(smem);
        for (int i = tid; i < nst * 320; i += 256) {
            const int w  = i / 320;
            const int f4 = i - w * 320;
            const int rc = min(max(rbase + w, 0), 255);
            dst4[i] = src4[rc * 320 + f4];
        }
        __syncthreads();

        const int oi = oi0 + rr;
        const int y  = (k == 0) ? oi : 255 - oi;

        if (!docrop) {
            // exact permutation: fy=0, fx=0, row y staged at slot y-rbase
            const float* rb = smem + (y - rbase) * ROWF;
            #pragma unroll
            for (int p = 0; p < 4; ++p) {
                const int oj = lane + 64 * p;
                const int xf = (k == 0) ? oj : 255 - oj;
                const int x  = flp ? 255 - xf : xf;
                #pragma unroll
                for (int ch = 0; ch < CH; ++ch) vout[p * 5 + ch] = rb[x * CH + ch];
            }
        } else {
            const float cy  = ((float)y + 0.5f) * scale - 0.5f + off0;
            const float flr = floorf(cy);
            const float fy  = cy - flr;
            const float* rbA = smem + ((int)flr - rbase) * ROWF;
            const float* rbB = rbA + ROWF;
            #pragma unroll
            for (int p = 0; p < 4; ++p) {
                const int oj = lane + 64 * p;
                const int xf = (k == 0) ? oj : 255 - oj;
                const int x  = flp ? 255 - xf : xf;
                const float cx  = ((float)x + 0.5f) * scale - 0.5f + off1;
                const float fl2 = floorf(cx);
                const float fx  = cx - fl2;
                const int c0 = min(max((int)fl2, 0), 255);
                const int c1 = min(max((int)fl2 + 1, 0), 255);
                #pragma unroll
                for (int ch = 0; ch < CH; ++ch) {
                    const float aV = rbA[c0 * CH + ch] + fx * (rbA[c1 * CH + ch] - rbA[c0 * CH + ch]);
                    const float dV = rbB[c0 * CH + ch] + fx * (rbB[c1 * CH + ch] - rbB[c0 * CH + ch]);
                    vout[p * 5 + ch] = aV + fy * (dV - aV);
                }
            }
        }
    } else {
        // ---- odd k: src col <- oi (wave-uniform per wave), src row <- oj ----
        const int xfA = (k == 1) ? 255 - oi0 : oi0;
        const int xfB = (k == 1) ? 255 - (oi0 + 3) : oi0 + 3;
        const int xA = flp ? 255 - xfA : xfA;
        const int xB = flp ? 255 - xfB : xfB;
        const int xmin = min(xA, xB);

        if (!docrop) {
            // exact permutation: stage 24-float col window (6 float4/row)
            const int base4 = min((xmin * CH) & ~3, ROWF - 24);
            const float4* rp = reinterpret_cast<const float4*>(
                crops + ((size_t)b * SDIM + tid) * ROWF + base4);
            const float4 q0 = rp[0], q1 = rp[1], q2 = rp[2];
            const float4 q3 = rp[3], q4 = rp[4], q5 = rp[5];
            smem[ 0*260+tid]=q0.x; smem[ 1*260+tid]=q0.y; smem[ 2*260+tid]=q0.z; smem[ 3*260+tid]=q0.w;
            smem[ 4*260+tid]=q1.x; smem[ 5*260+tid]=q1.y; smem[ 6*260+tid]=q1.z; smem[ 7*260+tid]=q1.w;
            smem[ 8*260+tid]=q2.x; smem[ 9*260+tid]=q2.y; smem[10*260+tid]=q2.z; smem[11*260+tid]=q2.w;
            smem[12*260+tid]=q3.x; smem[13*260+tid]=q3.y; smem[14*260+tid]=q3.z; smem[15*260+tid]=q3.w;
            smem[16*260+tid]=q4.x; smem[17*260+tid]=q4.y; smem[18*260+tid]=q4.z; smem[19*260+tid]=q4.w;
            smem[20*260+tid]=q5.x; smem[21*260+tid]=q5.y; smem[22*260+tid]=q5.z; smem[23*260+tid]=q5.w;
            __syncthreads();

            const int oi = oi0 + rr;
            const int xf = (k == 1) ? 255 - oi : oi;
            const int x  = flp ? 255 - xf : xf;
            const int slotA = x * CH - base4;
            #pragma unroll
            for (int p = 0; p < 4; ++p) {
                const int oj = lane + 64 * p;
                const int y  = (k == 1) ? oj : 255 - oj;
                #pragma unroll
                for (int ch = 0; ch < CH; ++ch)
                    vout[p * 5 + ch] = smem[(slotA + ch) * 260 + y];
            }
        } else {
            const float cxmin = ((float)xmin + 0.5f) * scale - 0.5f + off1;
            const int cbase = (int)floorf(cxmin);
            const int base4 = (cbase * CH) & ~3;
            const bool fastp = (cbase >= 0) && (cbase + 4 <= 255) && (base4 >= 0) && (base4 + 28 <= ROWF);

            if (fastp) {
                const float4* rp = reinterpret_cast<const float4*>(
                    crops + ((size_t)b * SDIM + tid) * ROWF + base4);
                const float4 q0 = rp[0], q1 = rp[1], q2 = rp[2], q3 = rp[3];
                const float4 q4 = rp[4], q5 = rp[5], q6 = rp[6];
                smem[ 0*260+tid]=q0.x; smem[ 1*260+tid]=q0.y; smem[ 2*260+tid]=q0.z; smem[ 3*260+tid]=q0.w;
                smem[ 4*260+tid]=q1.x; smem[ 5*260+tid]=q1.y; smem[ 6*260+tid]=q1.z; smem[ 7*260+tid]=q1.w;
                smem[ 8*260+tid]=q2.x; smem[ 9*260+tid]=q2.y; smem[10*260+tid]=q2.z; smem[11*260+tid]=q2.w;
                smem[12*260+tid]=q3.x; smem[13*260+tid]=q3.y; smem[14*260+tid]=q3.z; smem[15*260+tid]=q3.w;
                smem[16*260+tid]=q4.x; smem[17*260+tid]=q4.y; smem[18*260+tid]=q4.z; smem[19*260+tid]=q4.w;
                smem[20*260+tid]=q5.x; smem[21*260+tid]=q5.y; smem[22*260+tid]=q5.z; smem[23*260+tid]=q5.w;
                smem[24*260+tid]=q6.x; smem[25*260+tid]=q6.y; smem[26*260+tid]=q6.z; smem[27*260+tid]=q6.w;
            } else {
                #pragma unroll
                for (int w = 0; w < 28; ++w) {
                    const int f2 = base4 + w + ROWF;       // bias keeps div positive
                    const int c2 = f2 / 5;
                    const int ch = f2 - c2 * 5;
                    const int cc = min(max(c2 - 256, 0), 255);
                    smem[w * 260 + tid] = crops[((size_t)b * SDIM + tid) * ROWF + cc * CH + ch];
                }
            }
            __syncthreads();

            const int oi = oi0 + rr;
            const int xf = (k == 1) ? 255 - oi : oi;
            const int x  = flp ? 255 - xf : xf;
            const float cx  = ((float)x + 0.5f) * scale - 0.5f + off1;
            const float fl2 = floorf(cx);
            const float fx  = cx - fl2;
            const int slotA = (int)fl2 * CH - base4;   // pre-clamp slot; content clamped
            const int slotB = slotA + CH;

            #pragma unroll
            for (int p = 0; p < 4; ++p) {
                const int oj = lane + 64 * p;
                const int y  = (k == 1) ? oj : 255 - oj;
                const float cy  = ((float)y + 0.5f) * scale - 0.5f + off0;
                const float flr = floorf(cy);
                const float fy  = cy - flr;
                const int r0 = min(max((int)flr, 0), 255);
                const int r1 = min(max((int)flr + 1, 0), 255);
                #pragma unroll
                for (int ch = 0; ch < CH; ++ch) {
                    const float p00 = smem[(slotA + ch) * 260 + r0];
                    const float p01 = smem[(slotB + ch) * 260 + r0];
                    const float p10 = smem[(slotA + ch) * 260 + r1];
                    const float p11 = smem[(slotB + ch) * 260 + r1];
                    const float aV = p00 + fx * (p01 - p00);
                    const float dV = p10 + fx * (p11 - p10);
                    vout[p * 5 + ch] = aV + fy * (dV - aV);
                }
            }
        }
    }

    // ---- fused affine in registers ----
    float aa[5], ab[5];
    #pragma unroll
    for (int ch = 0; ch < CH; ++ch) { aa[ch] = prm[ch]; ab[ch] = prm[CH + ch]; }
    #pragma unroll
    for (int p = 0; p < 4; ++p)
        #pragma unroll
        for (int ch = 0; ch < CH; ++ch)
            vout[p * 5 + ch] = vout[p * 5 + ch] * aa[ch] + ab[ch];

    // ---- repack through LDS (stride-5 writes: conflict-free) + dense stores ----
    __syncthreads();   // staging no longer needed; reuse smem as obuf[4][1280]
    #pragma unroll
    for (int p = 0; p < 4; ++p) {
        const int oj = lane + 64 * p;
        #pragma unroll
        for (int ch = 0; ch < CH; ++ch)
            smem[rr * ROWF + oj * CH + ch] = vout[p * 5 + ch];
    }
    __syncthreads();

    const float4* ob4 = reinterpret_cast<const float4*>(smem);
    float4* dst = reinterpret_cast<float4*>(out + ((size_t)b * SDIM + oi0) * ROWF);
    #pragma unroll
    for (int q = 0; q < 5; ++q) dst[q * 256 + tid] = ob4[q * 256 + tid];
}

extern "C" void kernel_launch(void* const* d_in, const int* in_sizes, int n_in,
                              void* d_out, int out_size, void* d_ws, size_t ws_size,
                              hipStream_t stream) {
    const float* crops     = (const float*)d_in[0];
    const float* off_frac  = (const float*)d_in[1];
    const float* bright    = (const float*)d_in[2];
    const float* contrast  = (const float*)d_in[3];
    const int*   crop_size = (const int*)d_in[4];
    const int*   do_crop   = (const int*)d_in[5];
    const int*   flipb     = (const int*)d_in[6];
    const int*   rot_k     = (const int*)d_in[7];

    float* out  = (float*)d_out;
    float* part = (float*)d_ws;                 // [NCHUNK][64][CH]
    float* wbuf = (float*)d_ws + WBUF_OFF;      // [64][512]

    dim3 blk(256);
    aug_weights_kernel<<<dim3(64), blk, 0, stream>>>(off_frac, crop_size, do_crop, wbuf);
    aug_sums_kernel<<<dim3(NCHUNK, 64), blk, 0, stream>>>(crops, wbuf, part);
    aug_out_kernel<<<dim3(SDIM / 4, 64), blk, 0, stream>>>(crops, off_frac, crop_size, do_crop,
                                                           flipb, rot_k, part, bright, contrast, out);
}